// Round 8
// baseline (1455.655 us; speedup 1.0000x reference)
//
#include <hip/hip_runtime.h>
#include <hip/hip_bf16.h>
#include <math.h>

// Problem constants
#define L_ 1024
#define B_ 4
#define D_ 1024
#define E_ 8
#define K_ 2
#define H_ 4096
#define T_ (L_*B_)        // 4096 tokens
#define P_ (T_*K_)        // 8192 token-expert pairs
#define PPAD (P_+256)     // padded rows so partial 256-tiles can over-read safely

typedef unsigned short u16;
typedef __attribute__((ext_vector_type(4))) float f32x4;
typedef __attribute__((ext_vector_type(8))) short s16x8;

__device__ __forceinline__ u16 f2bf(float f) {
  uint32_t u = __float_as_uint(f);
  uint32_t r = (u + 0x7FFFu + ((u >> 16) & 1u)) >> 16;  // RNE
  return (u16)r;
}
// gelu tanh-approx in sigmoid form
__device__ __forceinline__ float gelu_fast(float v) {
  float u = v * (1.0f + 0.044715f * v * v);
  float t = __expf(-1.5957691216057308f * u);
  return v / (1.0f + t);
}

// ---------------------------------------------------------------------------
// fp32 [E][R][C] -> bf16 [E][C][R]  (transpose + convert, 64x64 LDS tiles)
// ---------------------------------------------------------------------------
template<int R, int C>
__global__ void convtrans(const float* __restrict__ in, u16* __restrict__ out) {
  __shared__ float tile[64][65];
  int e = blockIdx.z;
  int r0 = blockIdx.y * 64, c0 = blockIdx.x * 64;
  const float* src = in + (size_t)e * R * C;
  u16* dst = out + (size_t)e * R * C;
  int t = threadIdx.x;
  int tr = t >> 4, tc = (t & 15) * 4;
#pragma unroll
  for (int p = 0; p < 4; ++p) {
    int r = tr + p * 16;
    float4 v = *(const float4*)(src + (size_t)(r0 + r) * C + c0 + tc);
    tile[r][tc] = v.x; tile[r][tc+1] = v.y; tile[r][tc+2] = v.z; tile[r][tc+3] = v.w;
  }
  __syncthreads();
#pragma unroll
  for (int p = 0; p < 4; ++p) {
    int c = tr + p * 16;
    ushort4 o;
    o.x = f2bf(tile[tc+0][c]); o.y = f2bf(tile[tc+1][c]);
    o.z = f2bf(tile[tc+2][c]); o.w = f2bf(tile[tc+3][c]);
    *(ushort4*)(dst + (size_t)(c0 + c) * R + r0 + tc) = o;
  }
}

// ---------------------------------------------------------------------------
// Gating: one wave per token. fp32 logits (must match reference top-k).
// ---------------------------------------------------------------------------
__global__ void gating(const float* __restrict__ x, const float* __restrict__ task_param,
                       const float* __restrict__ gw_img, const float* __restrict__ gb_img,
                       const float* __restrict__ gw_txt, const float* __restrict__ gb_txt,
                       const float* __restrict__ tgw, const float* __restrict__ tgb,
                       const float* __restrict__ alpha_p, const int* __restrict__ is_text_p,
                       float4* __restrict__ sel_w, float* __restrict__ prob_part,
                       int* __restrict__ count_part) {
  __shared__ float wprob[4][8];
  __shared__ int wcnt[4][8];
  int wid = threadIdx.x >> 6, lane = threadIdx.x & 63;
  int t = blockIdx.x * 4 + wid;
  int b = t & (B_ - 1);
  int it = is_text_p[0];
  const float* gw = it ? gw_txt : gw_img;
  const float* gb = it ? gb_txt : gb_img;
  float alpha = alpha_p[0];
  const float* xr = x + (size_t)t * D_;
  const float* tp = task_param + (size_t)b * D_;
  float acc[8] = {0,0,0,0,0,0,0,0};
  float tac[8] = {0,0,0,0,0,0,0,0};
  for (int i = 0; i < D_/64; ++i) {
    int d = i * 64 + lane;
    float xv = xr[d], tv = tp[d];
#pragma unroll
    for (int e = 0; e < 8; ++e) {
      acc[e] += xv * gw[d*8 + e];
      tac[e] += tv * tgw[d*8 + e];
    }
  }
#pragma unroll
  for (int e = 0; e < 8; ++e) {
#pragma unroll
    for (int off = 32; off > 0; off >>= 1) {
      acc[e] += __shfl_xor(acc[e], off);
      tac[e] += __shfl_xor(tac[e], off);
    }
  }
  float lg[8];
#pragma unroll
  for (int e = 0; e < 8; ++e)
    lg[e] = (1.0f - alpha) * (acc[e] + gb[e]) + alpha * (tac[e] + tgb[e]);
  float m = lg[0];
#pragma unroll
  for (int e = 1; e < 8; ++e) m = fmaxf(m, lg[e]);
  float pr[8], ps = 0.f;
#pragma unroll
  for (int e = 0; e < 8; ++e) { pr[e] = expf(lg[e] - m); ps += pr[e]; }
  float inv = 1.0f / ps;
  int i0 = 0; float v0 = lg[0];
#pragma unroll
  for (int e = 1; e < 8; ++e) if (lg[e] > v0) { v0 = lg[e]; i0 = e; }
  int i1 = -1; float v1 = -1e30f;
#pragma unroll
  for (int e = 0; e < 8; ++e) if (e != i0 && lg[e] > v1) { v1 = lg[e]; i1 = e; }
  float ex = expf(v1 - v0);
  float w0 = 1.0f / (1.0f + ex), w1 = ex / (1.0f + ex);
  if (lane == 0) {
    sel_w[t] = make_float4(__int_as_float(i0), __int_as_float(i1), w0, w1);
#pragma unroll
    for (int e = 0; e < 8; ++e) {
      wprob[wid][e] = pr[e] * inv;
      wcnt[wid][e] = (i0 == e) + (i1 == e);
    }
  }
  __syncthreads();
  if (threadIdx.x < 8) {
    int e = threadIdx.x;
    prob_part[blockIdx.x * 8 + e] = wprob[0][e] + wprob[1][e] + wprob[2][e] + wprob[3][e];
    count_part[blockIdx.x * 8 + e] = wcnt[0][e] + wcnt[1][e] + wcnt[2][e] + wcnt[3][e];
  }
}

// ---------------------------------------------------------------------------
// Finalize: deterministic reduce of partials -> counts/offsets/cursors + l_aux
// ---------------------------------------------------------------------------
__global__ void finalize(const float* __restrict__ prob_part, const int* __restrict__ count_part,
                         int* __restrict__ counts, int* __restrict__ offs,
                         int* __restrict__ cursors, float* __restrict__ laux_out) {
  __shared__ float ps_[256];
  __shared__ int cs_[256];
  int t = threadIdx.x;
  int e = t & 7, s = t >> 3;
  float p = 0.f; int c = 0;
  for (int b = s; b < 1024; b += 32) { p += prob_part[b*8 + e]; c += count_part[b*8 + e]; }
  ps_[t] = p; cs_[t] = c;
  __syncthreads();
  for (int st = 16; st > 0; st >>= 1) {
    if (s < st) { ps_[t] += ps_[t + st*8]; cs_[t] += cs_[t + st*8]; }
    __syncthreads();
  }
  if (t == 0) {
    int off = 0; float laux = 0.f;
    for (int ee = 0; ee < 8; ++ee) {
      int cnt = cs_[ee];
      counts[ee] = cnt; offs[ee] = off; cursors[ee] = off; off += cnt;
      laux += (ps_[ee] * (1.0f/4096.0f)) * ((float)cnt * (1.0f/4096.0f));
    }
    *laux_out = laux;
  }
}

// ---------------------------------------------------------------------------
// Scatter + gather: assign bucket slots, record token->pair map, gather bf16 rows
// ---------------------------------------------------------------------------
__global__ void scatter_gather(const float* __restrict__ x, const float4* __restrict__ sel_w,
                               int* __restrict__ cursors, float* __restrict__ pair_w,
                               int* __restrict__ pair_idx, u16* __restrict__ Xg) {
  int wid = threadIdx.x >> 6, lane = threadIdx.x & 63;
  int t = blockIdx.x * 4 + wid;
  float4 sw = sel_w[t];
  int s0 = __float_as_int(sw.x), s1 = __float_as_int(sw.y);
  int p0 = 0, p1 = 0;
  if (lane == 0) {
    p0 = atomicAdd(&cursors[s0], 1);
    p1 = atomicAdd(&cursors[s1], 1);
  }
  p0 = __shfl(p0, 0); p1 = __shfl(p1, 0);
  if (lane == 0) {
    pair_w[p0] = sw.z; pair_w[p1] = sw.w;
    pair_idx[t*2] = p0; pair_idx[t*2+1] = p1;
  }
  const float* xr = x + (size_t)t * D_;
  u16* d0 = Xg + (size_t)p0 * D_;
  u16* d1 = Xg + (size_t)p1 * D_;
#pragma unroll
  for (int i = 0; i < 4; ++i) {
    int c = i * 256 + lane * 4;
    float4 v = *(const float4*)(xr + c);
    ushort4 o;
    o.x = f2bf(v.x); o.y = f2bf(v.y); o.z = f2bf(v.z); o.w = f2bf(v.w);
    *(ushort4*)(d0 + c) = o;
    *(ushort4*)(d1 + c) = o;
  }
}

// ---------------------------------------------------------------------------
// Grouped GEMM, 256x256 tile, BK=32, 8 waves (512 thr), 2-phase double-buffer
// (R5 structure — measured best: syncthreads only, compiler-managed waitcnts).
//
// CHANGE vs R5: BK 64->32 halves LDS to 64 KB -> 2 blocks/CU co-resident
// (launch_bounds(512,4) pins VGPR<=128 so 16 waves/CU fit). Grid doubled
// (JSLOTS 2x) -> finer work-unit balance; cross-block wave overlap (m114)
// hides the per-K-step barrier drain that scheduling rounds (R6/R7) could
// not remove at 1 block/CU.
//
// LDS swizzle (4 slots/row, re-derived): phys = kk ^ ((row>>1)&3).
// Frag read: 16 consecutive rows, fixed kk -> (row parity, slot) takes all
// 8 distinct values -> 2-way bank aliasing = free. (R6's ^(row&3) form only
// reached 4 -> 4-way conflict; this fixes that.) Involution; staging dest
// linear in tid (global_load_lds rule 21), global source carries the
// permutation (4-lane permuted runs within 64B windows -> coalesced).
//
// Roles: A(m)=weights(features), B(n)=tokens. wf=wid&1 (2x128 feat),
// wt=wid>>1 (4x64 tok); acc[8][4]; K=32 per MFMA -> 32 MFMA/wave/K-tile.
// KSPLIT (GEMM2): disjoint part buffers summed in combine (deterministic).
// Grid: 1-D, expert = gid&7 (XCD affinity).
// ---------------------------------------------------------------------------
template<int EPI, int KDIM, int KLEN, int NOUT, int NPANEL, int KSPLIT, int JSLOTS>
__global__ __launch_bounds__(512, 4)
void gemm256(const u16* __restrict__ Tok, const u16* __restrict__ Wt,
             const int* __restrict__ counts, const int* __restrict__ offs,
             const float* __restrict__ pair_w,
             u16* __restrict__ Hout, float* __restrict__ Cout) {
  int gid = blockIdx.x;
  int e = gid & 7;
  int idx = gid >> 3;
  int panel = idx % NPANEL; idx /= NPANEL;
  int ks = idx % KSPLIT;    idx /= KSPLIT;
  int j0 = idx;             // [0, JSLOTS)
  int ne = counts[e];
  int off = offs[e];
  int kbase = ks * KLEN;
  float* Cpart = Cout + (size_t)ks * P_ * D_;

  __shared__ u16 As[2][8192];   // 256 x 32 bf16 = 16 KB per buffer
  __shared__ u16 Bs[2][8192];
  int t = threadIdx.x, lane = t & 63, wid = t >> 6;
  int wf = wid & 1, wt = wid >> 1;

  const u16* Wg = Wt + (size_t)e * NOUT * KDIM + (size_t)panel * 256 * KDIM + kbase;

  // staging map: i covers slots [i*512 + t]; row = slot>>2, p = slot&3,
  // global kk = p ^ ((row>>1)&3)  (inverse == forward, involution).
  int goff[2], ldso[2];
#pragma unroll
  for (int i = 0; i < 2; ++i) {
    int slot = i * 512 + t;
    int row = slot >> 2;
    int p = slot & 3;
    int kk = p ^ ((row >> 1) & 3);
    goff[i] = row * KDIM + kk * 8;   // u16 offset from matrix base
    ldso[i] = slot * 8;              // linear u16 LDS offset
  }

  // fragment read offsets (u16): phys slot = (lane>>4) ^ ((row>>1)&3)
  int aoff[8], boff[4];
#pragma unroll
  for (int r = 0; r < 8; ++r) {
    int row = wf * 128 + r * 16 + (lane & 15);
    int p = (lane >> 4) ^ ((row >> 1) & 3);
    aoff[r] = (row * 4 + p) * 8;
  }
#pragma unroll
  for (int f = 0; f < 4; ++f) {
    int row = wt * 64 + f * 16 + (lane & 15);
    int p = (lane >> 4) ^ ((row >> 1) & 3);
    boff[f] = (row * 4 + p) * 8;
  }

  constexpr int NT = KLEN / 32;
  int lr = lane & 15, lg4 = (lane >> 4) * 4;

  for (int bx = j0; bx * 256 < ne; bx += JSLOTS) {
    const u16* Tg = Tok + (size_t)(off + bx * 256) * KDIM + kbase;
    f32x4 acc[8][4] = {};
    // prologue: stage K-tile 0 into buf 0
#pragma unroll
    for (int i = 0; i < 2; ++i) {
      __builtin_amdgcn_global_load_lds(
          (const __attribute__((address_space(1))) void*)(Wg + goff[i]),
          (__attribute__((address_space(3))) void*)(&As[0][ldso[i]]), 16, 0, 0);
      __builtin_amdgcn_global_load_lds(
          (const __attribute__((address_space(1))) void*)(Tg + goff[i]),
          (__attribute__((address_space(3))) void*)(&Bs[0][ldso[i]]), 16, 0, 0);
    }
    __syncthreads();
    int cur = 0;
    for (int tt = 0; tt < NT; ++tt) {
      if (tt + 1 < NT) {
        int k0 = (tt + 1) * 32;
        int nb = cur ^ 1;
#pragma unroll
        for (int i = 0; i < 2; ++i) {
          __builtin_amdgcn_global_load_lds(
              (const __attribute__((address_space(1))) void*)(Wg + goff[i] + k0),
              (__attribute__((address_space(3))) void*)(&As[nb][ldso[i]]), 16, 0, 0);
          __builtin_amdgcn_global_load_lds(
              (const __attribute__((address_space(1))) void*)(Tg + goff[i] + k0),
              (__attribute__((address_space(3))) void*)(&Bs[nb][ldso[i]]), 16, 0, 0);
        }
      }
      const u16* Ab = &As[cur][0]; const u16* Bb = &Bs[cur][0];
      s16x8 a[8], b[4];
#pragma unroll
      for (int r = 0; r < 8; ++r) a[r] = *(const s16x8*)(Ab + aoff[r]);
#pragma unroll
      for (int f = 0; f < 4; ++f) b[f] = *(const s16x8*)(Bb + boff[f]);
#pragma unroll
      for (int r = 0; r < 8; ++r)
#pragma unroll
        for (int f = 0; f < 4; ++f)
          acc[r][f] = __builtin_amdgcn_mfma_f32_16x16x32_bf16(a[r], b[f], acc[r][f], 0, 0, 0);
      __syncthreads();
      cur ^= 1;
    }

    // epilogue: token = wt*64 + f*16 + lr (col), feature = wf*128 + r*16 + lg4 + j
#pragma unroll
    for (int f = 0; f < 4; ++f) {
      int tokl = bx * 256 + wt * 64 + f * 16 + lr;
      if (tokl >= ne) continue;
      size_t grow = (size_t)(off + tokl);
      if (EPI == 0) {
#pragma unroll
        for (int r = 0; r < 8; ++r) {
          ushort4 o;
          o.x = f2bf(gelu_fast(acc[r][f][0]));
          o.y = f2bf(gelu_fast(acc[r][f][1]));
          o.z = f2bf(gelu_fast(acc[r][f][2]));
          o.w = f2bf(gelu_fast(acc[r][f][3]));
          *(ushort4*)(Hout + grow * NOUT + panel * 256 + wf * 128 + r * 16 + lg4) = o;
        }
      } else {
        float w = pair_w[grow];
#pragma unroll
        for (int r = 0; r < 8; ++r) {
          float4 o;
          o.x = acc[r][f][0] * w; o.y = acc[r][f][1] * w;
          o.z = acc[r][f][2] * w; o.w = acc[r][f][3] * w;
          *(float4*)(Cpart + grow * NOUT + panel * 256 + wf * 128 + r * 16 + lg4) = o;
        }
      }
    }
  }
}

// ---------------------------------------------------------------------------
// Combine: out[token] = sum over 2 pairs x 2 K-parts
// ---------------------------------------------------------------------------
__global__ void combine(const float* __restrict__ pair_out, const int* __restrict__ pair_idx,
                        float* __restrict__ out) {
  const float* part1 = pair_out + (size_t)P_ * D_;
  int t = blockIdx.x;
  int p0 = pair_idx[t*2], p1 = pair_idx[t*2+1];
  int c = threadIdx.x * 4;
  float4 a0 = *(const float4*)(pair_out + (size_t)p0 * D_ + c);
  float4 a1 = *(const float4*)(part1    + (size_t)p0 * D_ + c);
  float4 b0 = *(const float4*)(pair_out + (size_t)p1 * D_ + c);
  float4 b1 = *(const float4*)(part1    + (size_t)p1 * D_ + c);
  float4 o;
  o.x = (a0.x + a1.x) + (b0.x + b1.x);
  o.y = (a0.y + a1.y) + (b0.y + b1.y);
  o.z = (a0.z + a1.z) + (b0.z + b1.z);
  o.w = (a0.w + a1.w) + (b0.w + b1.w);
  *(float4*)(out + (size_t)t * D_ + c) = o;
}

// ---------------------------------------------------------------------------
// Workspace layout (bytes):
//   w1b  [E][H][D] bf16 @ 0           (67108864)  <- aliased by pair_out parts
//   w2b  [E][D][H] bf16 @ 67108864    (67108864)
//   Xg   [PPAD][D] bf16 @ 134217728   (17301504)
//   Hb   [PPAD][H] bf16 @ 151519232   (69206016)
//   small buffers @ 220725248
//   pair_out: 2 parts x [P_][D_] f32 @ 0 (67108864, aliases dead w1b)
// ---------------------------------------------------------------------------
extern "C" void kernel_launch(void* const* d_in, const int* in_sizes, int n_in,
                              void* d_out, int out_size, void* d_ws, size_t ws_size,
                              hipStream_t stream) {
  const float* inputs      = (const float*)d_in[0];
  const float* task_param  = (const float*)d_in[1];
  const float* gate_img_w  = (const float*)d_in[2];
  const float* gate_img_b  = (const float*)d_in[3];
  const float* gate_txt_w  = (const float*)d_in[4];
  const float* gate_txt_b  = (const float*)d_in[5];
  const float* task_gate_w = (const float*)d_in[6];
  const float* task_gate_b = (const float*)d_in[7];
  const float* alpha       = (const float*)d_in[8];
  const float* w1          = (const float*)d_in[9];
  const float* w2          = (const float*)d_in[10];
  const int*   is_text     = (const int*)d_in[11];
  float* out = (float*)d_out;

  char* ws = (char*)d_ws;
  u16* w1b = (u16*)(ws + 0);
  u16* w2b = (u16*)(ws + 67108864);
  u16* Xg  = (u16*)(ws + 134217728);
  u16* Hb  = (u16*)(ws + 151519232);
  float4* sel_w   = (float4*)(ws + 220725248);
  float* pair_w   = (float*)(ws + 220725248 + 65536);
  int* pair_idx   = (int*)(ws + 220725248 + 98816);
  float* prob_part= (float*)(ws + 220725248 + 131584);
  int* count_part = (int*)(ws + 220725248 + 164352);
  int* counters   = (int*)(ws + 220725248 + 197120);
  float* pair_out = (float*)(ws + 0);  // 2 parts, aliases dead w1b

  int* counts  = counters;
  int* offs    = counters + 8;
  int* cursors = counters + 16;

  convtrans<D_, H_><<<dim3(H_/64, D_/64, E_), 256, 0, stream>>>(w1, w1b);
  convtrans<H_, D_><<<dim3(D_/64, H_/64, E_), 256, 0, stream>>>(w2, w2b);
  gating<<<dim3(T_/4), 256, 0, stream>>>(inputs, task_param, gate_img_w, gate_img_b,
      gate_txt_w, gate_txt_b, task_gate_w, task_gate_b, alpha, is_text,
      sel_w, prob_part, count_part);
  finalize<<<dim3(1), 256, 0, stream>>>(prob_part, count_part, counts, offs, cursors,
      out + (size_t)T_ * D_);
  scatter_gather<<<dim3(T_/4), 256, 0, stream>>>(inputs, sel_w, cursors, pair_w, pair_idx, Xg);
  // GEMM1: Tok=Xg, W=w1b; K=1024 (NT=32), 16 panels, 4 token-slots. 512 blocks.
  gemm256<0, D_, D_, H_, 16, 1, 4><<<dim3(512), 512, 0, stream>>>(
      Xg, w1b, counts, offs, pair_w, Hb, (float*)nullptr);
  // GEMM2: Tok=Hb, W=w2b; K=4096 split 2x2048 (NT=64), 4 panels, 8 token-slots. 512 blocks.
  gemm256<1, H_, H_/2, D_, 4, 2, 8><<<dim3(512), 512, 0, stream>>>(
      Hb, w2b, counts, offs, pair_w, (u16*)nullptr, pair_out);
  combine<<<dim3(T_), 256, 0, stream>>>(pair_out, pair_idx, out);
}

// Round 9
// 583.049 us; speedup vs baseline: 2.4966x; 2.4966x over previous
//
#include <hip/hip_runtime.h>
#include <hip/hip_bf16.h>
#include <math.h>

// Problem constants
#define L_ 1024
#define B_ 4
#define D_ 1024
#define E_ 8
#define K_ 2
#define H_ 4096
#define T_ (L_*B_)        // 4096 tokens
#define P_ (T_*K_)        // 8192 token-expert pairs
#define PPAD (P_+256)     // padded rows so partial 256-tiles can over-read safely

typedef unsigned short u16;
typedef __attribute__((ext_vector_type(4))) float f32x4;
typedef __attribute__((ext_vector_type(8))) short s16x8;

__device__ __forceinline__ u16 f2bf(float f) {
  uint32_t u = __float_as_uint(f);
  uint32_t r = (u + 0x7FFFu + ((u >> 16) & 1u)) >> 16;  // RNE
  return (u16)r;
}
// gelu tanh-approx in sigmoid form
__device__ __forceinline__ float gelu_fast(float v) {
  float u = v * (1.0f + 0.044715f * v * v);
  float t = __expf(-1.5957691216057308f * u);
  return v / (1.0f + t);
}

// ---------------------------------------------------------------------------
// fp32 [E][R][C] -> bf16 [E][C][R]  (transpose + convert, 64x64 LDS tiles)
// ---------------------------------------------------------------------------
template<int R, int C>
__global__ void convtrans(const float* __restrict__ in, u16* __restrict__ out) {
  __shared__ float tile[64][65];
  int e = blockIdx.z;
  int r0 = blockIdx.y * 64, c0 = blockIdx.x * 64;
  const float* src = in + (size_t)e * R * C;
  u16* dst = out + (size_t)e * R * C;
  int t = threadIdx.x;
  int tr = t >> 4, tc = (t & 15) * 4;
#pragma unroll
  for (int p = 0; p < 4; ++p) {
    int r = tr + p * 16;
    float4 v = *(const float4*)(src + (size_t)(r0 + r) * C + c0 + tc);
    tile[r][tc] = v.x; tile[r][tc+1] = v.y; tile[r][tc+2] = v.z; tile[r][tc+3] = v.w;
  }
  __syncthreads();
#pragma unroll
  for (int p = 0; p < 4; ++p) {
    int c = tr + p * 16;
    ushort4 o;
    o.x = f2bf(tile[tc+0][c]); o.y = f2bf(tile[tc+1][c]);
    o.z = f2bf(tile[tc+2][c]); o.w = f2bf(tile[tc+3][c]);
    *(ushort4*)(dst + (size_t)(c0 + c) * R + r0 + tc) = o;
  }
}

// ---------------------------------------------------------------------------
// Gating: one wave per token. fp32 logits (must match reference top-k).
// ---------------------------------------------------------------------------
__global__ void gating(const float* __restrict__ x, const float* __restrict__ task_param,
                       const float* __restrict__ gw_img, const float* __restrict__ gb_img,
                       const float* __restrict__ gw_txt, const float* __restrict__ gb_txt,
                       const float* __restrict__ tgw, const float* __restrict__ tgb,
                       const float* __restrict__ alpha_p, const int* __restrict__ is_text_p,
                       float4* __restrict__ sel_w, float* __restrict__ prob_part,
                       int* __restrict__ count_part) {
  __shared__ float wprob[4][8];
  __shared__ int wcnt[4][8];
  int wid = threadIdx.x >> 6, lane = threadIdx.x & 63;
  int t = blockIdx.x * 4 + wid;
  int b = t & (B_ - 1);
  int it = is_text_p[0];
  const float* gw = it ? gw_txt : gw_img;
  const float* gb = it ? gb_txt : gb_img;
  float alpha = alpha_p[0];
  const float* xr = x + (size_t)t * D_;
  const float* tp = task_param + (size_t)b * D_;
  float acc[8] = {0,0,0,0,0,0,0,0};
  float tac[8] = {0,0,0,0,0,0,0,0};
  for (int i = 0; i < D_/64; ++i) {
    int d = i * 64 + lane;
    float xv = xr[d], tv = tp[d];
#pragma unroll
    for (int e = 0; e < 8; ++e) {
      acc[e] += xv * gw[d*8 + e];
      tac[e] += tv * tgw[d*8 + e];
    }
  }
#pragma unroll
  for (int e = 0; e < 8; ++e) {
#pragma unroll
    for (int off = 32; off > 0; off >>= 1) {
      acc[e] += __shfl_xor(acc[e], off);
      tac[e] += __shfl_xor(tac[e], off);
    }
  }
  float lg[8];
#pragma unroll
  for (int e = 0; e < 8; ++e)
    lg[e] = (1.0f - alpha) * (acc[e] + gb[e]) + alpha * (tac[e] + tgb[e]);
  float m = lg[0];
#pragma unroll
  for (int e = 1; e < 8; ++e) m = fmaxf(m, lg[e]);
  float pr[8], ps = 0.f;
#pragma unroll
  for (int e = 0; e < 8; ++e) { pr[e] = expf(lg[e] - m); ps += pr[e]; }
  float inv = 1.0f / ps;
  int i0 = 0; float v0 = lg[0];
#pragma unroll
  for (int e = 1; e < 8; ++e) if (lg[e] > v0) { v0 = lg[e]; i0 = e; }
  int i1 = -1; float v1 = -1e30f;
#pragma unroll
  for (int e = 0; e < 8; ++e) if (e != i0 && lg[e] > v1) { v1 = lg[e]; i1 = e; }
  float ex = expf(v1 - v0);
  float w0 = 1.0f / (1.0f + ex), w1 = ex / (1.0f + ex);
  if (lane == 0) {
    sel_w[t] = make_float4(__int_as_float(i0), __int_as_float(i1), w0, w1);
#pragma unroll
    for (int e = 0; e < 8; ++e) {
      wprob[wid][e] = pr[e] * inv;
      wcnt[wid][e] = (i0 == e) + (i1 == e);
    }
  }
  __syncthreads();
  if (threadIdx.x < 8) {
    int e = threadIdx.x;
    prob_part[blockIdx.x * 8 + e] = wprob[0][e] + wprob[1][e] + wprob[2][e] + wprob[3][e];
    count_part[blockIdx.x * 8 + e] = wcnt[0][e] + wcnt[1][e] + wcnt[2][e] + wcnt[3][e];
  }
}

// ---------------------------------------------------------------------------
// Finalize: deterministic reduce of partials -> counts/offsets/cursors + l_aux
// ---------------------------------------------------------------------------
__global__ void finalize(const float* __restrict__ prob_part, const int* __restrict__ count_part,
                         int* __restrict__ counts, int* __restrict__ offs,
                         int* __restrict__ cursors, float* __restrict__ laux_out) {
  __shared__ float ps_[256];
  __shared__ int cs_[256];
  int t = threadIdx.x;
  int e = t & 7, s = t >> 3;
  float p = 0.f; int c = 0;
  for (int b = s; b < 1024; b += 32) { p += prob_part[b*8 + e]; c += count_part[b*8 + e]; }
  ps_[t] = p; cs_[t] = c;
  __syncthreads();
  for (int st = 16; st > 0; st >>= 1) {
    if (s < st) { ps_[t] += ps_[t + st*8]; cs_[t] += cs_[t + st*8]; }
    __syncthreads();
  }
  if (t == 0) {
    int off = 0; float laux = 0.f;
    for (int ee = 0; ee < 8; ++ee) {
      int cnt = cs_[ee];
      counts[ee] = cnt; offs[ee] = off; cursors[ee] = off; off += cnt;
      laux += (ps_[ee] * (1.0f/4096.0f)) * ((float)cnt * (1.0f/4096.0f));
    }
    *laux_out = laux;
  }
}

// ---------------------------------------------------------------------------
// Scatter + gather: assign bucket slots, record token->pair map, gather bf16 rows
// ---------------------------------------------------------------------------
__global__ void scatter_gather(const float* __restrict__ x, const float4* __restrict__ sel_w,
                               int* __restrict__ cursors, float* __restrict__ pair_w,
                               int* __restrict__ pair_idx, u16* __restrict__ Xg) {
  int wid = threadIdx.x >> 6, lane = threadIdx.x & 63;
  int t = blockIdx.x * 4 + wid;
  float4 sw = sel_w[t];
  int s0 = __float_as_int(sw.x), s1 = __float_as_int(sw.y);
  int p0 = 0, p1 = 0;
  if (lane == 0) {
    p0 = atomicAdd(&cursors[s0], 1);
    p1 = atomicAdd(&cursors[s1], 1);
  }
  p0 = __shfl(p0, 0); p1 = __shfl(p1, 0);
  if (lane == 0) {
    pair_w[p0] = sw.z; pair_w[p1] = sw.w;
    pair_idx[t*2] = p0; pair_idx[t*2+1] = p1;
  }
  const float* xr = x + (size_t)t * D_;
  u16* d0 = Xg + (size_t)p0 * D_;
  u16* d1 = Xg + (size_t)p1 * D_;
#pragma unroll
  for (int i = 0; i < 4; ++i) {
    int c = i * 256 + lane * 4;
    float4 v = *(const float4*)(xr + c);
    ushort4 o;
    o.x = f2bf(v.x); o.y = f2bf(v.y); o.z = f2bf(v.z); o.w = f2bf(v.w);
    *(ushort4*)(d0 + c) = o;
    *(ushort4*)(d1 + c) = o;
  }
}

// ---------------------------------------------------------------------------
// Grouped GEMM, 256x256 tile, BK=32, 8 waves (512 thr), 2-phase double-buffer
// (R5 structure: syncthreads only, compiler-managed waitcnts).
//
// R8 lesson baked in: __launch_bounds__ 2nd arg is CUDA-semantics MIN BLOCKS
// PER CU. (512,4) forced 32 waves/CU -> 64 VGPR -> acc spills -> 1.8 GB
// scratch traffic. (512,2) caps VGPR at 128 (R5-proven no-spill for this
// body). With BK=32 the LDS is 64 KB -> 2 blocks/CU now fit by BOTH LDS and
// VGPR -> cross-block wave overlap (m114) hides the per-K-step barrier drain
// that R6/R7 scheduling could not remove at 1 block/CU.
//
// LDS swizzle (4 slots/row, R8-verified ZERO conflicts): phys = kk ^
// ((row>>1)&3). Involution; staging dest linear in tid (rule 21), global
// source carries the permutation (4-lane permuted runs within 64B windows).
//
// Roles: A(m)=weights(features), B(n)=tokens. wf=wid&1 (2x128 feat),
// wt=wid>>1 (4x64 tok); acc[8][4]; 32 MFMA/wave/K-tile.
// KSPLIT (GEMM2): disjoint part buffers summed in combine (deterministic).
// Grid: 1-D, expert = gid&7 (XCD affinity).
// ---------------------------------------------------------------------------
template<int EPI, int KDIM, int KLEN, int NOUT, int NPANEL, int KSPLIT, int JSLOTS>
__global__ __launch_bounds__(512, 2)
void gemm256(const u16* __restrict__ Tok, const u16* __restrict__ Wt,
             const int* __restrict__ counts, const int* __restrict__ offs,
             const float* __restrict__ pair_w,
             u16* __restrict__ Hout, float* __restrict__ Cout) {
  int gid = blockIdx.x;
  int e = gid & 7;
  int idx = gid >> 3;
  int panel = idx % NPANEL; idx /= NPANEL;
  int ks = idx % KSPLIT;    idx /= KSPLIT;
  int j0 = idx;             // [0, JSLOTS)
  int ne = counts[e];
  int off = offs[e];
  int kbase = ks * KLEN;
  float* Cpart = Cout + (size_t)ks * P_ * D_;

  __shared__ u16 As[2][8192];   // 256 x 32 bf16 = 16 KB per buffer
  __shared__ u16 Bs[2][8192];
  int t = threadIdx.x, lane = t & 63, wid = t >> 6;
  int wf = wid & 1, wt = wid >> 1;

  const u16* Wg = Wt + (size_t)e * NOUT * KDIM + (size_t)panel * 256 * KDIM + kbase;

  // staging map: i covers slots [i*512 + t]; row = slot>>2, p = slot&3,
  // global kk = p ^ ((row>>1)&3)  (inverse == forward, involution).
  int goff[2], ldso[2];
#pragma unroll
  for (int i = 0; i < 2; ++i) {
    int slot = i * 512 + t;
    int row = slot >> 2;
    int p = slot & 3;
    int kk = p ^ ((row >> 1) & 3);
    goff[i] = row * KDIM + kk * 8;   // u16 offset from matrix base
    ldso[i] = slot * 8;              // linear u16 LDS offset
  }

  // fragment read offsets (u16): phys slot = (lane>>4) ^ ((row>>1)&3)
  int aoff[8], boff[4];
#pragma unroll
  for (int r = 0; r < 8; ++r) {
    int row = wf * 128 + r * 16 + (lane & 15);
    int p = (lane >> 4) ^ ((row >> 1) & 3);
    aoff[r] = (row * 4 + p) * 8;
  }
#pragma unroll
  for (int f = 0; f < 4; ++f) {
    int row = wt * 64 + f * 16 + (lane & 15);
    int p = (lane >> 4) ^ ((row >> 1) & 3);
    boff[f] = (row * 4 + p) * 8;
  }

  constexpr int NT = KLEN / 32;
  int lr = lane & 15, lg4 = (lane >> 4) * 4;

  for (int bx = j0; bx * 256 < ne; bx += JSLOTS) {
    const u16* Tg = Tok + (size_t)(off + bx * 256) * KDIM + kbase;
    f32x4 acc[8][4] = {};
    // prologue: stage K-tile 0 into buf 0
#pragma unroll
    for (int i = 0; i < 2; ++i) {
      __builtin_amdgcn_global_load_lds(
          (const __attribute__((address_space(1))) void*)(Wg + goff[i]),
          (__attribute__((address_space(3))) void*)(&As[0][ldso[i]]), 16, 0, 0);
      __builtin_amdgcn_global_load_lds(
          (const __attribute__((address_space(1))) void*)(Tg + goff[i]),
          (__attribute__((address_space(3))) void*)(&Bs[0][ldso[i]]), 16, 0, 0);
    }
    __syncthreads();
    int cur = 0;
    for (int tt = 0; tt < NT; ++tt) {
      if (tt + 1 < NT) {
        int k0 = (tt + 1) * 32;
        int nb = cur ^ 1;
#pragma unroll
        for (int i = 0; i < 2; ++i) {
          __builtin_amdgcn_global_load_lds(
              (const __attribute__((address_space(1))) void*)(Wg + goff[i] + k0),
              (__attribute__((address_space(3))) void*)(&As[nb][ldso[i]]), 16, 0, 0);
          __builtin_amdgcn_global_load_lds(
              (const __attribute__((address_space(1))) void*)(Tg + goff[i] + k0),
              (__attribute__((address_space(3))) void*)(&Bs[nb][ldso[i]]), 16, 0, 0);
        }
      }
      const u16* Ab = &As[cur][0]; const u16* Bb = &Bs[cur][0];
      s16x8 a[8], b[4];
#pragma unroll
      for (int r = 0; r < 8; ++r) a[r] = *(const s16x8*)(Ab + aoff[r]);
#pragma unroll
      for (int f = 0; f < 4; ++f) b[f] = *(const s16x8*)(Bb + boff[f]);
#pragma unroll
      for (int r = 0; r < 8; ++r)
#pragma unroll
        for (int f = 0; f < 4; ++f)
          acc[r][f] = __builtin_amdgcn_mfma_f32_16x16x32_bf16(a[r], b[f], acc[r][f], 0, 0, 0);
      __syncthreads();
      cur ^= 1;
    }

    // epilogue: token = wt*64 + f*16 + lr (col), feature = wf*128 + r*16 + lg4 + j
#pragma unroll
    for (int f = 0; f < 4; ++f) {
      int tokl = bx * 256 + wt * 64 + f * 16 + lr;
      if (tokl >= ne) continue;
      size_t grow = (size_t)(off + tokl);
      if (EPI == 0) {
#pragma unroll
        for (int r = 0; r < 8; ++r) {
          ushort4 o;
          o.x = f2bf(gelu_fast(acc[r][f][0]));
          o.y = f2bf(gelu_fast(acc[r][f][1]));
          o.z = f2bf(gelu_fast(acc[r][f][2]));
          o.w = f2bf(gelu_fast(acc[r][f][3]));
          *(ushort4*)(Hout + grow * NOUT + panel * 256 + wf * 128 + r * 16 + lg4) = o;
        }
      } else {
        float w = pair_w[grow];
#pragma unroll
        for (int r = 0; r < 8; ++r) {
          float4 o;
          o.x = acc[r][f][0] * w; o.y = acc[r][f][1] * w;
          o.z = acc[r][f][2] * w; o.w = acc[r][f][3] * w;
          *(float4*)(Cpart + grow * NOUT + panel * 256 + wf * 128 + r * 16 + lg4) = o;
        }
      }
    }
  }
}

// ---------------------------------------------------------------------------
// Combine: out[token] = sum over 2 pairs x 2 K-parts
// ---------------------------------------------------------------------------
__global__ void combine(const float* __restrict__ pair_out, const int* __restrict__ pair_idx,
                        float* __restrict__ out) {
  const float* part1 = pair_out + (size_t)P_ * D_;
  int t = blockIdx.x;
  int p0 = pair_idx[t*2], p1 = pair_idx[t*2+1];
  int c = threadIdx.x * 4;
  float4 a0 = *(const float4*)(pair_out + (size_t)p0 * D_ + c);
  float4 a1 = *(const float4*)(part1    + (size_t)p0 * D_ + c);
  float4 b0 = *(const float4*)(pair_out + (size_t)p1 * D_ + c);
  float4 b1 = *(const float4*)(part1    + (size_t)p1 * D_ + c);
  float4 o;
  o.x = (a0.x + a1.x) + (b0.x + b1.x);
  o.y = (a0.y + a1.y) + (b0.y + b1.y);
  o.z = (a0.z + a1.z) + (b0.z + b1.z);
  o.w = (a0.w + a1.w) + (b0.w + b1.w);
  *(float4*)(out + (size_t)t * D_ + c) = o;
}

// ---------------------------------------------------------------------------
// Workspace layout (bytes):
//   w1b  [E][H][D] bf16 @ 0           (67108864)  <- aliased by pair_out parts
//   w2b  [E][D][H] bf16 @ 67108864    (67108864)
//   Xg   [PPAD][D] bf16 @ 134217728   (17301504)
//   Hb   [PPAD][H] bf16 @ 151519232   (69206016)
//   small buffers @ 220725248
//   pair_out: 2 parts x [P_][D_] f32 @ 0 (67108864, aliases dead w1b)
// ---------------------------------------------------------------------------
extern "C" void kernel_launch(void* const* d_in, const int* in_sizes, int n_in,
                              void* d_out, int out_size, void* d_ws, size_t ws_size,
                              hipStream_t stream) {
  const float* inputs      = (const float*)d_in[0];
  const float* task_param  = (const float*)d_in[1];
  const float* gate_img_w  = (const float*)d_in[2];
  const float* gate_img_b  = (const float*)d_in[3];
  const float* gate_txt_w  = (const float*)d_in[4];
  const float* gate_txt_b  = (const float*)d_in[5];
  const float* task_gate_w = (const float*)d_in[6];
  const float* task_gate_b = (const float*)d_in[7];
  const float* alpha       = (const float*)d_in[8];
  const float* w1          = (const float*)d_in[9];
  const float* w2          = (const float*)d_in[10];
  const int*   is_text     = (const int*)d_in[11];
  float* out = (float*)d_out;

  char* ws = (char*)d_ws;
  u16* w1b = (u16*)(ws + 0);
  u16* w2b = (u16*)(ws + 67108864);
  u16* Xg  = (u16*)(ws + 134217728);
  u16* Hb  = (u16*)(ws + 151519232);
  float4* sel_w   = (float4*)(ws + 220725248);
  float* pair_w   = (float*)(ws + 220725248 + 65536);
  int* pair_idx   = (int*)(ws + 220725248 + 98816);
  float* prob_part= (float*)(ws + 220725248 + 131584);
  int* count_part = (int*)(ws + 220725248 + 164352);
  int* counters   = (int*)(ws + 220725248 + 197120);
  float* pair_out = (float*)(ws + 0);  // 2 parts, aliases dead w1b

  int* counts  = counters;
  int* offs    = counters + 8;
  int* cursors = counters + 16;

  convtrans<D_, H_><<<dim3(H_/64, D_/64, E_), 256, 0, stream>>>(w1, w1b);
  convtrans<H_, D_><<<dim3(D_/64, H_/64, E_), 256, 0, stream>>>(w2, w2b);
  gating<<<dim3(T_/4), 256, 0, stream>>>(inputs, task_param, gate_img_w, gate_img_b,
      gate_txt_w, gate_txt_b, task_gate_w, task_gate_b, alpha, is_text,
      sel_w, prob_part, count_part);
  finalize<<<dim3(1), 256, 0, stream>>>(prob_part, count_part, counts, offs, cursors,
      out + (size_t)T_ * D_);
  scatter_gather<<<dim3(T_/4), 256, 0, stream>>>(inputs, sel_w, cursors, pair_w, pair_idx, Xg);
  // GEMM1: Tok=Xg, W=w1b; K=1024 (NT=32), 16 panels, 4 token-slots. 512 blocks.
  gemm256<0, D_, D_, H_, 16, 1, 4><<<dim3(512), 512, 0, stream>>>(
      Xg, w1b, counts, offs, pair_w, Hb, (float*)nullptr);
  // GEMM2: Tok=Hb, W=w2b; K=4096 split 2x2048 (NT=64), 4 panels, 8 token-slots. 512 blocks.
  gemm256<1, H_, H_/2, D_, 4, 2, 8><<<dim3(512), 512, 0, stream>>>(
      Hb, w2b, counts, offs, pair_w, (u16*)nullptr, pair_out);
  combine<<<dim3(T_), 256, 0, stream>>>(pair_out, pair_idx, out);
}

// Round 10
// 477.800 us; speedup vs baseline: 3.0466x; 1.2203x over previous
//
#include <hip/hip_runtime.h>
#include <hip/hip_bf16.h>
#include <math.h>

// Problem constants
#define L_ 1024
#define B_ 4
#define D_ 1024
#define E_ 8
#define K_ 2
#define H_ 4096
#define T_ (L_*B_)        // 4096 tokens
#define P_ (T_*K_)        // 8192 token-expert pairs
#define PPAD (P_+256)     // padded rows so partial 256-tiles can over-read safely

typedef unsigned short u16;
typedef __attribute__((ext_vector_type(4))) float f32x4;
typedef __attribute__((ext_vector_type(8))) short s16x8;

__device__ __forceinline__ u16 f2bf(float f) {
  uint32_t u = __float_as_uint(f);
  uint32_t r = (u + 0x7FFFu + ((u >> 16) & 1u)) >> 16;  // RNE
  return (u16)r;
}
// gelu tanh-approx in sigmoid form
__device__ __forceinline__ float gelu_fast(float v) {
  float u = v * (1.0f + 0.044715f * v * v);
  float t = __expf(-1.5957691216057308f * u);
  return v / (1.0f + t);
}

// ---------------------------------------------------------------------------
// meta layout (ints): counts[0:8) offs[8:16) cursors[16:24) nbx[24:32)
//                     ub1[32:41) ub2[41:50) tick1@50 tick2@51
// ---------------------------------------------------------------------------

// ---------------------------------------------------------------------------
// fp32 [E][R][C] -> bf16 [E][C][R]  (transpose + convert, 64x64 LDS tiles)
// ---------------------------------------------------------------------------
template<int R, int C>
__global__ void convtrans(const float* __restrict__ in, u16* __restrict__ out) {
  __shared__ float tile[64][65];
  int e = blockIdx.z;
  int r0 = blockIdx.y * 64, c0 = blockIdx.x * 64;
  const float* src = in + (size_t)e * R * C;
  u16* dst = out + (size_t)e * R * C;
  int t = threadIdx.x;
  int tr = t >> 4, tc = (t & 15) * 4;
#pragma unroll
  for (int p = 0; p < 4; ++p) {
    int r = tr + p * 16;
    float4 v = *(const float4*)(src + (size_t)(r0 + r) * C + c0 + tc);
    tile[r][tc] = v.x; tile[r][tc+1] = v.y; tile[r][tc+2] = v.z; tile[r][tc+3] = v.w;
  }
  __syncthreads();
#pragma unroll
  for (int p = 0; p < 4; ++p) {
    int c = tr + p * 16;
    ushort4 o;
    o.x = f2bf(tile[tc+0][c]); o.y = f2bf(tile[tc+1][c]);
    o.z = f2bf(tile[tc+2][c]); o.w = f2bf(tile[tc+3][c]);
    *(ushort4*)(dst + (size_t)(c0 + c) * R + r0 + tc) = o;
  }
}

// ---------------------------------------------------------------------------
// Gating: one wave per token. fp32 logits (must match reference top-k).
// ---------------------------------------------------------------------------
__global__ void gating(const float* __restrict__ x, const float* __restrict__ task_param,
                       const float* __restrict__ gw_img, const float* __restrict__ gb_img,
                       const float* __restrict__ gw_txt, const float* __restrict__ gb_txt,
                       const float* __restrict__ tgw, const float* __restrict__ tgb,
                       const float* __restrict__ alpha_p, const int* __restrict__ is_text_p,
                       float4* __restrict__ sel_w, float* __restrict__ prob_part,
                       int* __restrict__ count_part) {
  __shared__ float wprob[4][8];
  __shared__ int wcnt[4][8];
  int wid = threadIdx.x >> 6, lane = threadIdx.x & 63;
  int t = blockIdx.x * 4 + wid;
  int b = t & (B_ - 1);
  int it = is_text_p[0];
  const float* gw = it ? gw_txt : gw_img;
  const float* gb = it ? gb_txt : gb_img;
  float alpha = alpha_p[0];
  const float* xr = x + (size_t)t * D_;
  const float* tp = task_param + (size_t)b * D_;
  float acc[8] = {0,0,0,0,0,0,0,0};
  float tac[8] = {0,0,0,0,0,0,0,0};
  for (int i = 0; i < D_/64; ++i) {
    int d = i * 64 + lane;
    float xv = xr[d], tv = tp[d];
#pragma unroll
    for (int e = 0; e < 8; ++e) {
      acc[e] += xv * gw[d*8 + e];
      tac[e] += tv * tgw[d*8 + e];
    }
  }
#pragma unroll
  for (int e = 0; e < 8; ++e) {
#pragma unroll
    for (int off = 32; off > 0; off >>= 1) {
      acc[e] += __shfl_xor(acc[e], off);
      tac[e] += __shfl_xor(tac[e], off);
    }
  }
  float lg[8];
#pragma unroll
  for (int e = 0; e < 8; ++e)
    lg[e] = (1.0f - alpha) * (acc[e] + gb[e]) + alpha * (tac[e] + tgb[e]);
  float m = lg[0];
#pragma unroll
  for (int e = 1; e < 8; ++e) m = fmaxf(m, lg[e]);
  float pr[8], ps = 0.f;
#pragma unroll
  for (int e = 0; e < 8; ++e) { pr[e] = expf(lg[e] - m); ps += pr[e]; }
  float inv = 1.0f / ps;
  int i0 = 0; float v0 = lg[0];
#pragma unroll
  for (int e = 1; e < 8; ++e) if (lg[e] > v0) { v0 = lg[e]; i0 = e; }
  int i1 = -1; float v1 = -1e30f;
#pragma unroll
  for (int e = 0; e < 8; ++e) if (e != i0 && lg[e] > v1) { v1 = lg[e]; i1 = e; }
  float ex = expf(v1 - v0);
  float w0 = 1.0f / (1.0f + ex), w1 = ex / (1.0f + ex);
  if (lane == 0) {
    sel_w[t] = make_float4(__int_as_float(i0), __int_as_float(i1), w0, w1);
#pragma unroll
    for (int e = 0; e < 8; ++e) {
      wprob[wid][e] = pr[e] * inv;
      wcnt[wid][e] = (i0 == e) + (i1 == e);
    }
  }
  __syncthreads();
  if (threadIdx.x < 8) {
    int e = threadIdx.x;
    prob_part[blockIdx.x * 8 + e] = wprob[0][e] + wprob[1][e] + wprob[2][e] + wprob[3][e];
    count_part[blockIdx.x * 8 + e] = wcnt[0][e] + wcnt[1][e] + wcnt[2][e] + wcnt[3][e];
  }
}

// ---------------------------------------------------------------------------
// Finalize: deterministic reduce -> counts/offs/cursors + unit tables + l_aux
// ---------------------------------------------------------------------------
__global__ void finalize(const float* __restrict__ prob_part, const int* __restrict__ count_part,
                         int* __restrict__ meta, float* __restrict__ laux_out) {
  __shared__ float ps_[256];
  __shared__ int cs_[256];
  int t = threadIdx.x;
  int e = t & 7, s = t >> 3;
  float p = 0.f; int c = 0;
  for (int b = s; b < 1024; b += 32) { p += prob_part[b*8 + e]; c += count_part[b*8 + e]; }
  ps_[t] = p; cs_[t] = c;
  __syncthreads();
  for (int st = 16; st > 0; st >>= 1) {
    if (s < st) { ps_[t] += ps_[t + st*8]; cs_[t] += cs_[t + st*8]; }
    __syncthreads();
  }
  if (t == 0) {
    int off = 0; float laux = 0.f;
    int u1 = 0, u2 = 0;
    for (int ee = 0; ee < 8; ++ee) {
      int cnt = cs_[ee];
      meta[ee] = cnt;          // counts
      meta[8 + ee] = off;      // offs
      meta[16 + ee] = off;     // cursors
      int nb = (cnt + 255) >> 8;
      meta[24 + ee] = nb;      // nbx
      meta[32 + ee] = u1;      // ub1 (GEMM1: 16 panels x nb)
      meta[41 + ee] = u2;      // ub2 (GEMM2: 4 panels x nb x 2 ksplit)
      u1 += 16 * nb;
      u2 += 4 * nb * 2;
      off += cnt;
      laux += (ps_[ee] * (1.0f/4096.0f)) * ((float)cnt * (1.0f/4096.0f));
    }
    meta[32 + 8] = u1;         // ub1[8] = U1 total
    meta[41 + 8] = u2;         // ub2[8] = U2 total
    meta[50] = 0;              // tick1
    meta[51] = 0;              // tick2
    *laux_out = laux;
  }
}

// ---------------------------------------------------------------------------
// Scatter + gather: assign bucket slots, record token->pair map, gather bf16 rows
// ---------------------------------------------------------------------------
__global__ void scatter_gather(const float* __restrict__ x, const float4* __restrict__ sel_w,
                               int* __restrict__ cursors, float* __restrict__ pair_w,
                               int* __restrict__ pair_idx, u16* __restrict__ Xg) {
  int wid = threadIdx.x >> 6, lane = threadIdx.x & 63;
  int t = blockIdx.x * 4 + wid;
  float4 sw = sel_w[t];
  int s0 = __float_as_int(sw.x), s1 = __float_as_int(sw.y);
  int p0 = 0, p1 = 0;
  if (lane == 0) {
    p0 = atomicAdd(&cursors[s0], 1);
    p1 = atomicAdd(&cursors[s1], 1);
  }
  p0 = __shfl(p0, 0); p1 = __shfl(p1, 0);
  if (lane == 0) {
    pair_w[p0] = sw.z; pair_w[p1] = sw.w;
    pair_idx[t*2] = p0; pair_idx[t*2+1] = p1;
  }
  const float* xr = x + (size_t)t * D_;
  u16* d0 = Xg + (size_t)p0 * D_;
  u16* d1 = Xg + (size_t)p1 * D_;
#pragma unroll
  for (int i = 0; i < 4; ++i) {
    int c = i * 256 + lane * 4;
    float4 v = *(const float4*)(xr + c);
    ushort4 o;
    o.x = f2bf(v.x); o.y = f2bf(v.y); o.z = f2bf(v.z); o.w = f2bf(v.w);
    *(ushort4*)(d0 + c) = o;
    *(ushort4*)(d1 + c) = o;
  }
}

// ---------------------------------------------------------------------------
// Grouped GEMM, 256x256 tile, BK=64, 8 waves, 2-phase (R5 structure — the
// measured-best of 4 schedule variants: R5 175 > R7 8ph 185 > R9 BK32 208 >
// R6 ring 215 µs).
//
// CHANGE vs R5: DYNAMIC TICKET dispatch over a flattened unit list.
// Unit = (expert, panel, bx[, ks]); panel-major within expert so consecutive
// tickets share the same 512 KB weight panel (weights stay L2-hot).
// Balance: every block grabs the next unit -> per-block work differs by <=1
// unit, independent of per-expert token counts (the static-slot tail was
// ~1.5-2x). Output per unit is a pure function of the unit -> any grab order
// yields identical results; tickets re-zeroed by finalize every launch.
// XCD-affinity is dropped; R9 evidence (GEMM2 FETCH 67MB < operands) shows
// L3 carries the reuse.
//
// LDS swizzle (R5-verified 0 conflicts): 8 x 16B slots/row, phys = kk^(row&7).
// Staging dest linear in tid (rule 21); global source carries the inverse.
// Roles: A(m)=weights(features), B(n)=tokens; wf=wid&1, wt=wid>>1; acc[8][4].
// __launch_bounds__(512,2): min-2-blocks/CU caps VGPR at 128 (R8 lesson:
// 2nd arg is CUDA min-blocks semantics; (512,4) -> 64 VGPR -> spill disaster).
// ---------------------------------------------------------------------------
template<int EPI, int KDIM, int KLEN, int NOUT, int NPANEL, int KSPLIT>
__global__ __launch_bounds__(512, 2)
void gemm256(const u16* __restrict__ Tok, const u16* __restrict__ Wt,
             int* __restrict__ meta, const float* __restrict__ pair_w,
             u16* __restrict__ Hout, float* __restrict__ Cout) {
  const int* offs = meta + 8;
  const int* nbx  = meta + 24;
  const int* ub   = (EPI == 0) ? meta + 32 : meta + 41;
  int* tick       = meta + ((EPI == 0) ? 50 : 51);

  __shared__ u16 As[2][16384];   // 256 x 64 bf16 = 32 KB per buffer
  __shared__ u16 Bs[2][16384];
  __shared__ int s_u;
  int t = threadIdx.x, lane = t & 63, wid = t >> 6;
  int wf = wid & 1, wt = wid >> 1;

  // staging map: i covers slots [i*512 + t]; row = slot>>3,
  // kk = (slot&7) ^ (row&7) (involution).
  int goff[4]; int ldso[4];
#pragma unroll
  for (int i = 0; i < 4; ++i) {
    int slot = i * 512 + t;
    int row = slot >> 3;
    int kk = (slot & 7) ^ (row & 7);
    goff[i] = row * KDIM + kk * 8;
    ldso[i] = slot * 8;
  }

  // fragment read offsets (u16): phys = (row*8 + (kk ^ (row&7)))*8
  int aoff[8][2], boff[4][2];
#pragma unroll
  for (int r = 0; r < 8; ++r) {
    int row = wf * 128 + r * 16 + (lane & 15);
#pragma unroll
    for (int h = 0; h < 2; ++h) {
      int kk = h * 4 + (lane >> 4);
      aoff[r][h] = (row * 8 + (kk ^ (row & 7))) * 8;
    }
  }
#pragma unroll
  for (int f = 0; f < 4; ++f) {
    int row = wt * 64 + f * 16 + (lane & 15);
#pragma unroll
    for (int h = 0; h < 2; ++h) {
      int kk = h * 4 + (lane >> 4);
      boff[f][h] = (row * 8 + (kk ^ (row & 7))) * 8;
    }
  }

  constexpr int NT = KLEN / 64;
  int lr = lane & 15, lg4 = (lane >> 4) * 4;
  int Utot = ub[8];

  for (;;) {
    if (t == 0) s_u = atomicAdd(tick, 1);
    __syncthreads();               // broadcast ticket; also fences LDS reuse
    int u = s_u;
    if (u >= Utot) break;
    // decode unit: expert (8-entry prefix scan), then panel-major local
    int e = 0;
    while (u >= ub[e + 1]) ++e;
    int ul = u - ub[e];
    int nb = nbx[e];
    int panel = ul / (nb * KSPLIT);
    int rem   = ul - panel * (nb * KSPLIT);
    int bx    = rem / KSPLIT;
    int ks    = rem - bx * KSPLIT;
    int ne  = meta[e];
    int off = offs[e];
    int kbase = ks * KLEN;
    float* Cpart = Cout + (size_t)ks * P_ * D_;
    const u16* Wg = Wt + (size_t)e * NOUT * KDIM + (size_t)panel * 256 * KDIM + kbase;
    const u16* Tg = Tok + (size_t)(off + bx * 256) * KDIM + kbase;

    f32x4 acc[8][4] = {};
    // prologue: stage K-tile 0 into buf 0
#pragma unroll
    for (int i = 0; i < 4; ++i) {
      __builtin_amdgcn_global_load_lds(
          (const __attribute__((address_space(1))) void*)(Wg + goff[i]),
          (__attribute__((address_space(3))) void*)(&As[0][ldso[i]]), 16, 0, 0);
      __builtin_amdgcn_global_load_lds(
          (const __attribute__((address_space(1))) void*)(Tg + goff[i]),
          (__attribute__((address_space(3))) void*)(&Bs[0][ldso[i]]), 16, 0, 0);
    }
    __syncthreads();
    int cur = 0;
    for (int tt = 0; tt < NT; ++tt) {
      if (tt + 1 < NT) {
        int k0 = (tt + 1) * 64;
        int nbuf = cur ^ 1;
#pragma unroll
        for (int i = 0; i < 4; ++i) {
          __builtin_amdgcn_global_load_lds(
              (const __attribute__((address_space(1))) void*)(Wg + goff[i] + k0),
              (__attribute__((address_space(3))) void*)(&As[nbuf][ldso[i]]), 16, 0, 0);
          __builtin_amdgcn_global_load_lds(
              (const __attribute__((address_space(1))) void*)(Tg + goff[i] + k0),
              (__attribute__((address_space(3))) void*)(&Bs[nbuf][ldso[i]]), 16, 0, 0);
        }
      }
      const u16* Ab = &As[cur][0]; const u16* Bb = &Bs[cur][0];
#pragma unroll
      for (int h = 0; h < 2; ++h) {
        s16x8 a[8], b[4];
#pragma unroll
        for (int r = 0; r < 8; ++r) a[r] = *(const s16x8*)(Ab + aoff[r][h]);
#pragma unroll
        for (int f = 0; f < 4; ++f) b[f] = *(const s16x8*)(Bb + boff[f][h]);
#pragma unroll
        for (int r = 0; r < 8; ++r)
#pragma unroll
          for (int f = 0; f < 4; ++f)
            acc[r][f] = __builtin_amdgcn_mfma_f32_16x16x32_bf16(a[r], b[f], acc[r][f], 0, 0, 0);
      }
      __syncthreads();
      cur ^= 1;
    }

    // epilogue: token = wt*64 + f*16 + lr (col), feature = wf*128 + r*16 + lg4 + j
#pragma unroll
    for (int f = 0; f < 4; ++f) {
      int tokl = bx * 256 + wt * 64 + f * 16 + lr;
      if (tokl >= ne) continue;
      size_t grow = (size_t)(off + tokl);
      if (EPI == 0) {
#pragma unroll
        for (int r = 0; r < 8; ++r) {
          ushort4 o;
          o.x = f2bf(gelu_fast(acc[r][f][0]));
          o.y = f2bf(gelu_fast(acc[r][f][1]));
          o.z = f2bf(gelu_fast(acc[r][f][2]));
          o.w = f2bf(gelu_fast(acc[r][f][3]));
          *(ushort4*)(Hout + grow * NOUT + panel * 256 + wf * 128 + r * 16 + lg4) = o;
        }
      } else {
        float w = pair_w[grow];
#pragma unroll
        for (int r = 0; r < 8; ++r) {
          float4 o;
          o.x = acc[r][f][0] * w; o.y = acc[r][f][1] * w;
          o.z = acc[r][f][2] * w; o.w = acc[r][f][3] * w;
          *(float4*)(Cpart + grow * NOUT + panel * 256 + wf * 128 + r * 16 + lg4) = o;
        }
      }
    }
  }
}

// ---------------------------------------------------------------------------
// Combine: out[token] = sum over 2 pairs x 2 K-parts
// ---------------------------------------------------------------------------
__global__ void combine(const float* __restrict__ pair_out, const int* __restrict__ pair_idx,
                        float* __restrict__ out) {
  const float* part1 = pair_out + (size_t)P_ * D_;
  int t = blockIdx.x;
  int p0 = pair_idx[t*2], p1 = pair_idx[t*2+1];
  int c = threadIdx.x * 4;
  float4 a0 = *(const float4*)(pair_out + (size_t)p0 * D_ + c);
  float4 a1 = *(const float4*)(part1    + (size_t)p0 * D_ + c);
  float4 b0 = *(const float4*)(pair_out + (size_t)p1 * D_ + c);
  float4 b1 = *(const float4*)(part1    + (size_t)p1 * D_ + c);
  float4 o;
  o.x = (a0.x + a1.x) + (b0.x + b1.x);
  o.y = (a0.y + a1.y) + (b0.y + b1.y);
  o.z = (a0.z + a1.z) + (b0.z + b1.z);
  o.w = (a0.w + a1.w) + (b0.w + b1.w);
  *(float4*)(out + (size_t)t * D_ + c) = o;
}

// ---------------------------------------------------------------------------
// Workspace layout (bytes):
//   w1b  [E][H][D] bf16 @ 0           (67108864)  <- aliased by pair_out parts
//   w2b  [E][D][H] bf16 @ 67108864    (67108864)
//   Xg   [PPAD][D] bf16 @ 134217728   (17301504)
//   Hb   [PPAD][H] bf16 @ 151519232   (69206016)
//   small buffers @ 220725248
//   pair_out: 2 parts x [P_][D_] f32 @ 0 (67108864, aliases dead w1b)
// ---------------------------------------------------------------------------
extern "C" void kernel_launch(void* const* d_in, const int* in_sizes, int n_in,
                              void* d_out, int out_size, void* d_ws, size_t ws_size,
                              hipStream_t stream) {
  const float* inputs      = (const float*)d_in[0];
  const float* task_param  = (const float*)d_in[1];
  const float* gate_img_w  = (const float*)d_in[2];
  const float* gate_img_b  = (const float*)d_in[3];
  const float* gate_txt_w  = (const float*)d_in[4];
  const float* gate_txt_b  = (const float*)d_in[5];
  const float* task_gate_w = (const float*)d_in[6];
  const float* task_gate_b = (const float*)d_in[7];
  const float* alpha       = (const float*)d_in[8];
  const float* w1          = (const float*)d_in[9];
  const float* w2          = (const float*)d_in[10];
  const int*   is_text     = (const int*)d_in[11];
  float* out = (float*)d_out;

  char* ws = (char*)d_ws;
  u16* w1b = (u16*)(ws + 0);
  u16* w2b = (u16*)(ws + 67108864);
  u16* Xg  = (u16*)(ws + 134217728);
  u16* Hb  = (u16*)(ws + 151519232);
  float4* sel_w   = (float4*)(ws + 220725248);
  float* pair_w   = (float*)(ws + 220725248 + 65536);
  int* pair_idx   = (int*)(ws + 220725248 + 98816);
  float* prob_part= (float*)(ws + 220725248 + 131584);
  int* count_part = (int*)(ws + 220725248 + 164352);
  int* meta       = (int*)(ws + 220725248 + 197120);
  float* pair_out = (float*)(ws + 0);  // 2 parts, aliases dead w1b

  convtrans<D_, H_><<<dim3(H_/64, D_/64, E_), 256, 0, stream>>>(w1, w1b);
  convtrans<H_, D_><<<dim3(D_/64, H_/64, E_), 256, 0, stream>>>(w2, w2b);
  gating<<<dim3(T_/4), 256, 0, stream>>>(inputs, task_param, gate_img_w, gate_img_b,
      gate_txt_w, gate_txt_b, task_gate_w, task_gate_b, alpha, is_text,
      sel_w, prob_part, count_part);
  finalize<<<dim3(1), 256, 0, stream>>>(prob_part, count_part, meta,
      out + (size_t)T_ * D_);
  scatter_gather<<<dim3(T_/4), 256, 0, stream>>>(inputs, sel_w, meta + 16, pair_w, pair_idx, Xg);
  // GEMM1: Tok=Xg, W=w1b; K=1024 (NT=16), 16 panels, no ksplit. Ticketed.
  gemm256<0, D_, D_, H_, 16, 1><<<dim3(256), 512, 0, stream>>>(
      Xg, w1b, meta, pair_w, Hb, (float*)nullptr);
  // GEMM2: Tok=Hb, W=w2b; K=4096 split 2x2048 (NT=32), 4 panels. Ticketed.
  gemm256<1, H_, H_/2, D_, 4, 2><<<dim3(256), 512, 0, stream>>>(
      Hb, w2b, meta, pair_w, (u16*)nullptr, pair_out);
  combine<<<dim3(T_), 256, 0, stream>>>(pair_out, pair_idx, out);
}